// Round 14
// baseline (100.236 us; speedup 1.0000x reference)
//
#include <hip/hip_runtime.h>
#include <math.h>

#define PIX 4096
typedef unsigned short ushort_t;
typedef unsigned int uint_t;
typedef __attribute__((ext_vector_type(8))) short bf16x8;
typedef __attribute__((ext_vector_type(16))) float f32x16;

// ---- ws layout ----
// floats:
//   APart [8ks][4h][4096][17] @ 0   (cols 0-15 = PV partial, col16 = den partial)
// ushort region @ float offset 2228224:
//   QH  [4][4096][16] @ 0           (Q RN-bf16, QSCALE folded)
//   QKB [128][4096]   @ 262144      (k ch 0..63, v ch 64..127, RN-bf16)
//   KF  [4][288][512] @ 786432      (per chunk: 512 bf16, lane-frag order)
//   VF  [4][288][512] @ 1376256     (per chunk: 2 halves x 256, bf16, frag order)
#define OFF_USHORT 2228224
#define U_QH 0
#define U_QKB 262144
#define U_KF 786432
#define U_VF 1376256

#define QSCALE 0.36067376022224087f   // 0.25 * log2(e)

#if defined(__has_builtin)
#if __has_builtin(__builtin_amdgcn_exp2f)
#define EXP2F(x) __builtin_amdgcn_exp2f(x)
#endif
#if __has_builtin(__builtin_amdgcn_perm)
#define PKHI16(u1, u0) __builtin_amdgcn_perm((u1), (u0), 0x07060302u)
#endif
#endif
#ifndef EXP2F
#define EXP2F(x) exp2f(x)
#endif
#ifndef PKHI16
#define PKHI16(u1, u0) (((u0) >> 16) | ((u1) & 0xFFFF0000u))
#endif

__device__ __forceinline__ ushort_t rn_bf16(float x) {
    uint_t u = __float_as_uint(x);
    return (ushort_t)((u + 0x7FFFu + ((u >> 16) & 1u)) >> 16);
}

// ---------------- K1: qkv projection, sync-free 32x32 MFMA tiles, inline rstd ----------------
__global__ __launch_bounds__(256)
void k_qkv(const float* __restrict__ x, const float* __restrict__ w_qkv,
           const float* __restrict__ ln_w, ushort_t* __restrict__ QH,
           ushort_t* __restrict__ QKB)
{
    const int tid = threadIdx.x;
    const int w = tid >> 6, l = tid & 63;
    const int col = l & 31, half = l >> 5;
    const int id = (int)blockIdx.x * 4 + w;   // 0..767
    const int ot = id >> 7;                    // 0..5
    const int pt = id & 127;                   // 0..127
    const int obase = ot * 32;
    const int gpx = pt * 32 + col;

    float s = 0.f, s2 = 0.f;
    #pragma unroll 16
    for (int c = 0; c < 64; ++c) {
        float v = x[c * PIX + gpx];
        s += v; s2 = fmaf(v, v, s2);
    }
    const float mean = s * 0.015625f;
    const float var  = fmaf(-mean, mean, s2 * 0.015625f);
    const float rs   = 1.0f / sqrtf(var + 1e-5f);

    f32x16 acc = {0,0,0,0,0,0,0,0,0,0,0,0,0,0,0,0};
    const float* wrow = w_qkv + (obase + col) * 64;
    #pragma unroll
    for (int s4 = 0; s4 < 4; ++s4) {
        const int kbase = s4 * 16 + half * 8;
        float t8[8];
        *(float4*)&t8[0] = *(const float4*)&wrow[kbase];
        *(float4*)&t8[4] = *(const float4*)&wrow[kbase + 4];
        union { uint_t u[4]; bf16x8 b; } wa;
        #pragma unroll
        for (int j = 0; j < 4; ++j)
            wa.u[j] = (uint_t)rn_bf16(t8[2 * j]) | ((uint_t)rn_bf16(t8[2 * j + 1]) << 16);
        const float4 lwa = *(const float4*)&ln_w[kbase];
        const float4 lwb = *(const float4*)&ln_w[kbase + 4];
        float b8[8];
        b8[0] = x[(kbase + 0) * PIX + gpx] * rs * lwa.x;
        b8[1] = x[(kbase + 1) * PIX + gpx] * rs * lwa.y;
        b8[2] = x[(kbase + 2) * PIX + gpx] * rs * lwa.z;
        b8[3] = x[(kbase + 3) * PIX + gpx] * rs * lwa.w;
        b8[4] = x[(kbase + 4) * PIX + gpx] * rs * lwb.x;
        b8[5] = x[(kbase + 5) * PIX + gpx] * rs * lwb.y;
        b8[6] = x[(kbase + 6) * PIX + gpx] * rs * lwb.z;
        b8[7] = x[(kbase + 7) * PIX + gpx] * rs * lwb.w;
        union { uint_t u[4]; bf16x8 b; } xb;
        #pragma unroll
        for (int j = 0; j < 4; ++j)
            xb.u[j] = (uint_t)rn_bf16(b8[2 * j]) | ((uint_t)rn_bf16(b8[2 * j + 1]) << 16);
        acc = __builtin_amdgcn_mfma_f32_32x32x16_bf16(wa.b, xb.b, acc, 0, 0, 0);
    }

    #pragma unroll
    for (int j = 0; j < 16; ++j) {
        const int o = obase + (j & 3) + 8 * (j >> 2) + 4 * half;
        if (o < 64) {
            QH[((o >> 4) * PIX + gpx) * 16 + (o & 15)] = rn_bf16(acc[j] * QSCALE);
        } else {
            QKB[(o - 64) * PIX + gpx] = rn_bf16(acc[j]);
        }
    }
}

// ---------------- K2: K + V unfold-gather from bf16, 8 elems/thread (unchanged) ----------------
__global__ __launch_bounds__(256)
void k_prep_kv(const ushort_t* __restrict__ QKB,
               ushort_t* __restrict__ KF, ushort_t* __restrict__ VF)
{
    const int bid = blockIdx.x;
    const int tid = threadIdx.x;
    if (bid < 288) {
        const int t = bid * 256 + tid;          // < 73728
        const int h = t / 18432; int r = t - h * 18432;
        const int i = r >> 6;   const int l = r & 63;
        const int col = l & 31, rl = l >> 5;
        const int m = i * 32 + col;
        const int cc = m / 576;  const int r3 = m - cc * 576;
        const int orr = r3 / 48; const int r4 = r3 - orr * 48;
        const int oc = r4 >> 2, wg = r4 & 3;
        const int row = wg * 16 + rl * 8 + orr - 2;
        const bool rowOk = (unsigned)row < 64u;
        const ushort_t* src = QKB + (h * 16 + cc) * PIX + row * 64 + (oc - 2);
        union { ushort_t us[8]; bf16x8 b; } o8;
        #pragma unroll
        for (int j = 0; j < 8; ++j) {
            const int colp = j * 8 + oc - 2;
            o8.us[j] = (rowOk && (unsigned)colp < 64u) ? src[j * 8] : (ushort_t)0;
        }
        *(bf16x8*)&KF[(h * 288 + i) * 512 + l * 8] = o8.b;
    } else {
        const int t = (bid - 288) * 256 + tid;  // < 73728
        const int h = t / 18432; int r = t - h * 18432;
        const int i = r >> 6;   const int r2 = r & 63;
        const int half = r2 >> 5; const int rl = (r2 >> 4) & 1; const int colD = r2 & 15;
        const int d = colD;
        const int vcolp = (d & 7) * 8 - 2;
        const int rbase = (d >> 3) * 8 - 2;
        const ushort_t* srcp = QKB + (64 + h * 16) * PIX;
        union { ushort_t us[8]; bf16x8 b; } o8;
        #pragma unroll
        for (int j2 = 0; j2 < 8; ++j2) {
            const int m = i * 32 + half * 16 + rl * 4 + (j2 & 3) + 8 * (j2 >> 2);
            const int cc = m / 576;  const int r3 = m - cc * 576;
            const int orr = r3 / 48; const int r4 = r3 - orr * 48;
            const int oc = r4 >> 2, wg = r4 & 3;
            const int row  = wg * 16 + rbase + orr;
            const int colp = vcolp + oc;
            const bool ok = ((unsigned)row < 64u) && ((unsigned)colp < 64u);
            o8.us[j2] = ok ? srcp[cc * PIX + row * 64 + colp] : (ushort_t)0;
        }
        *(bf16x8*)&VF[(h * 288 + i) * 512 + half * 256 + (rl * 16 + colD) * 8] = o8.b;
    }
}

// ---------------- K3: MFMA attention, software-pipelined softmax (S one chunk ahead) ----------------
// grid 256 x 512 (8 waves = 8 key-splits). bid: x=bid&7 -> h=x>>1, tile LSB=x&1.
__global__ __launch_bounds__(512)
void k_attn(const ushort_t* __restrict__ QH,
            const ushort_t* __restrict__ KF, const ushort_t* __restrict__ VF,
            float* __restrict__ APart)
{
    const int tid = threadIdx.x;
    const int w   = tid >> 6;       // ks = w
    const int l   = tid & 63;
    const int col = l & 31;
    const int rl  = l >> 5;

    const int bid  = blockIdx.x;
    const int x    = bid & 7;
    const int h    = x >> 1;
    const int tile = ((bid >> 3) << 1) | (x & 1);   // 0..63, 64 queries each
    const int qbase = tile * 64;

    const ushort_t* Qb = QH + ((h << 12) + qbase + col) * 16 + rl * 8;
    const bf16x8 qh0 = *(const bf16x8*)&Qb[0];
    const bf16x8 qh1 = *(const bf16x8*)&Qb[512];

    f32x16 acc0 = {0,0,0,0,0,0,0,0,0,0,0,0,0,0,0,0};
    f32x16 acc1 = {0,0,0,0,0,0,0,0,0,0,0,0,0,0,0,0};
    const f32x16 zero = {0,0,0,0,0,0,0,0,0,0,0,0,0,0,0,0};

    union { uint_t u[4]; bf16x8 b; } vconst;
    const uint_t cfill = (col == 16) ? 0x3F803F80u : 0u;
    vconst.u[0] = cfill; vconst.u[1] = cfill; vconst.u[2] = cfill; vconst.u[3] = cfill;

    const ushort_t* kb = KF + (h * 288 + w * 36) * 512;
    const ushort_t* vb = VF + (h * 288 + w * 36) * 512;
    const int vl = (rl * 16 + (col & 15)) * 8;
    const bool vload = (col < 16);

    // --- prologue: chunk 0 loaded + scored; chunk 1 loaded ---
    bf16x8 kA = *(const bf16x8*)&kb[l * 8];
    bf16x8 v0C = vconst.b, v1C = vconst.b;
    if (vload) {
        v0C = *(const bf16x8*)&vb[vl];
        v1C = *(const bf16x8*)&vb[256 + vl];
    }
    f32x16 Sa = __builtin_amdgcn_mfma_f32_32x32x16_bf16(kA, qh0, zero, 0, 0, 0);
    f32x16 Sb = __builtin_amdgcn_mfma_f32_32x32x16_bf16(kA, qh1, zero, 0, 0, 0);

    bf16x8 kN = *(const bf16x8*)&kb[512 + l * 8];
    bf16x8 v0N = vconst.b, v1N = vconst.b;
    if (vload) {
        v0N = *(const bf16x8*)&vb[512 + vl];
        v1N = *(const bf16x8*)&vb[512 + 256 + vl];
    }

    for (int i = 0; i < 36; ++i) {
        // snapshot chunk i+1 regs; issue loads for chunk i+2
        const bf16x8 kQ = kN;
        const bf16x8 v0Q = v0N, v1Q = v1N;
        if (i < 34) {
            const int off = (i + 2) * 512;
            kN = *(const bf16x8*)&kb[off + l * 8];
            if (vload) {
                v0N = *(const bf16x8*)&vb[off + vl];
                v1N = *(const bf16x8*)&vb[off + 256 + vl];
            }
        }

        // exp/pack/PV for chunk i (S computed last iteration -> no stall),
        // while S for chunk i+1 issues on the matrix pipe.
        f32x16 SnA = zero, SnB = zero;
        if (i < 35) {
            SnA = __builtin_amdgcn_mfma_f32_32x32x16_bf16(kQ, qh0, zero, 0, 0, 0);
            SnB = __builtin_amdgcn_mfma_f32_32x32x16_bf16(kQ, qh1, zero, 0, 0, 0);
        }

        {
            float p[16];
            #pragma unroll
            for (int r = 0; r < 16; ++r) p[r] = EXP2F(Sa[r]);
            union { uint_t u[4]; bf16x8 b; } A0, A1;
            #pragma unroll
            for (int j = 0; j < 4; ++j) {
                A0.u[j] = PKHI16(__float_as_uint(p[2 * j + 1]), __float_as_uint(p[2 * j]));
                A1.u[j] = PKHI16(__float_as_uint(p[8 + 2 * j + 1]), __float_as_uint(p[8 + 2 * j]));
            }
            acc0 = __builtin_amdgcn_mfma_f32_32x32x16_bf16(A0.b, v0C, acc0, 0, 0, 0);
            acc0 = __builtin_amdgcn_mfma_f32_32x32x16_bf16(A1.b, v1C, acc0, 0, 0, 0);
        }
        {
            float p[16];
            #pragma unroll
            for (int r = 0; r < 16; ++r) p[r] = EXP2F(Sb[r]);
            union { uint_t u[4]; bf16x8 b; } A0, A1;
            #pragma unroll
            for (int j = 0; j < 4; ++j) {
                A0.u[j] = PKHI16(__float_as_uint(p[2 * j + 1]), __float_as_uint(p[2 * j]));
                A1.u[j] = PKHI16(__float_as_uint(p[8 + 2 * j + 1]), __float_as_uint(p[8 + 2 * j]));
            }
            acc1 = __builtin_amdgcn_mfma_f32_32x32x16_bf16(A0.b, v0C, acc1, 0, 0, 0);
            acc1 = __builtin_amdgcn_mfma_f32_32x32x16_bf16(A1.b, v1C, acc1, 0, 0, 0);
        }

        // rotate pipeline state
        Sa = SnA; Sb = SnB;
        v0C = v0Q; v1C = v1Q;
    }

    if (col <= 16) {
        float* base = APart + ((size_t)(w * 4 + h) << 12) * 17;
        #pragma unroll
        for (int j = 0; j < 16; ++j) {
            const int q = qbase + (j & 3) + 8 * (j >> 2) + 4 * rl;
            base[q * 17 + col]        = acc0[j];
            base[(q + 32) * 17 + col] = acc1[j];
        }
    }
}

// ---------------- K4: partial combine (8-way) + divide + output projection (unchanged) ----------------
__global__ __launch_bounds__(256)
void k_proj(const float* __restrict__ APart, const float* __restrict__ w_out,
            float* __restrict__ out)
{
    __shared__ float asum[16 * 72];
    __shared__ float wo[64 * 68];
    __shared__ float as2[16 * 68];
    __shared__ float rdn[64];
    const int tid = threadIdx.x;
    const int pbase = blockIdx.x * 16;

    for (int idx = tid; idx < 1088; idx += 256) {
        int q_l = idx / 68; int rem = idx - q_l * 68;
        int h = rem / 17;  int c17 = rem - h * 17;
        float s = 0.f;
        #pragma unroll
        for (int ks = 0; ks < 8; ++ks)
            s += APart[((size_t)((ks * 4 + h) * PIX + pbase + q_l)) * 17 + c17];
        asum[q_l * 72 + h * 17 + c17] = s;
    }
    for (int idx = tid; idx < 4096; idx += 256)
        wo[(idx >> 6) * 68 + (idx & 63)] = w_out[idx];
    __syncthreads();
    if (tid < 64) {
        int h = tid >> 4, px = tid & 15;
        rdn[tid] = 1.0f / asum[px * 72 + h * 17 + 16];
    }
    __syncthreads();
    for (int idx = tid; idx < 1024; idx += 256) {
        int px = idx >> 6, ii = idx & 63;
        int h = ii >> 4, d = ii & 15;
        as2[px * 68 + ii] = asum[px * 72 + h * 17 + d] * rdn[h * 16 + px];
    }
    __syncthreads();

    const int pl = tid & 15;
    const int og = tid >> 4;
    float a0 = 0.f, a1 = 0.f, a2 = 0.f, a3 = 0.f;
    for (int c = 0; c < 64; c += 4) {
        const float4 xv = *(const float4*)&as2[pl * 68 + c];
        const float4 w0 = *(const float4*)&wo[(og * 4 + 0) * 68 + c];
        const float4 w1 = *(const float4*)&wo[(og * 4 + 1) * 68 + c];
        const float4 w2 = *(const float4*)&wo[(og * 4 + 2) * 68 + c];
        const float4 w3 = *(const float4*)&wo[(og * 4 + 3) * 68 + c];
        a0 = fmaf(xv.x, w0.x, fmaf(xv.y, w0.y, fmaf(xv.z, w0.z, fmaf(xv.w, w0.w, a0))));
        a1 = fmaf(xv.x, w1.x, fmaf(xv.y, w1.y, fmaf(xv.z, w1.z, fmaf(xv.w, w1.w, a1))));
        a2 = fmaf(xv.x, w2.x, fmaf(xv.y, w2.y, fmaf(xv.z, w2.z, fmaf(xv.w, w2.w, a2))));
        a3 = fmaf(xv.x, w3.x, fmaf(xv.y, w3.y, fmaf(xv.z, w3.z, fmaf(xv.w, w3.w, a3))));
    }
    out[(og * 4 + 0) * PIX + pbase + pl] = a0;
    out[(og * 4 + 1) * PIX + pbase + pl] = a1;
    out[(og * 4 + 2) * PIX + pbase + pl] = a2;
    out[(og * 4 + 3) * PIX + pbase + pl] = a3;
}

extern "C" void kernel_launch(void* const* d_in, const int* in_sizes, int n_in,
                              void* d_out, int out_size, void* d_ws, size_t ws_size,
                              hipStream_t stream)
{
    const float* x     = (const float*)d_in[0];
    const float* w_qkv = (const float*)d_in[1];
    const float* w_out = (const float*)d_in[2];
    const float* ln_w  = (const float*)d_in[3];
    float* out = (float*)d_out;
    float* ws  = (float*)d_ws;

    float* APart = ws;
    ushort_t* U  = (ushort_t*)(ws + OFF_USHORT);
    ushort_t* QH  = U + U_QH;
    ushort_t* QKB = U + U_QKB;
    ushort_t* KF  = U + U_KF;
    ushort_t* VF  = U + U_VF;

    k_qkv     <<<dim3(192), dim3(256), 0, stream>>>(x, w_qkv, ln_w, QH, QKB);
    k_prep_kv <<<dim3(576), dim3(256), 0, stream>>>(QKB, KF, VF);
    k_attn    <<<dim3(256), dim3(512), 0, stream>>>(QH, KF, VF, APart);
    k_proj    <<<dim3(256), dim3(256), 0, stream>>>(APart, w_out, out);
}

// Round 15
// 91.786 us; speedup vs baseline: 1.0921x; 1.0921x over previous
//
#include <hip/hip_runtime.h>
#include <math.h>

#define PIX 4096
typedef unsigned short ushort_t;
typedef unsigned int uint_t;
typedef __attribute__((ext_vector_type(8))) short bf16x8;
typedef __attribute__((ext_vector_type(16))) float f32x16;

// ---- ws layout ----
// floats:
//   AO [4096][64] @ 0              (attn output, den-divided, [px][h*16+d])
// ushort region @ float offset 2228224:
//   QH  [4][4096][16] @ 0          (Q RN-bf16, QSCALE folded)
//   QKB [128][4096]   @ 262144     (k ch 0..63, v ch 64..127, RN-bf16)
//   KF  [4][288][512] @ 786432     (per chunk: 512 bf16, lane-frag order)
//   VF  [4][288][512] @ 1376256    (per chunk: 2 halves x 256, bf16, frag order)
#define OFF_USHORT 2228224
#define U_QH 0
#define U_QKB 262144
#define U_KF 786432
#define U_VF 1376256

#define QSCALE 0.36067376022224087f   // 0.25 * log2(e)

#if defined(__has_builtin)
#if __has_builtin(__builtin_amdgcn_exp2f)
#define EXP2F(x) __builtin_amdgcn_exp2f(x)
#endif
#if __has_builtin(__builtin_amdgcn_perm)
#define PKHI16(u1, u0) __builtin_amdgcn_perm((u1), (u0), 0x07060302u)
#endif
#endif
#ifndef EXP2F
#define EXP2F(x) exp2f(x)
#endif
#ifndef PKHI16
#define PKHI16(u1, u0) (((u0) >> 16) | ((u1) & 0xFFFF0000u))
#endif

__device__ __forceinline__ ushort_t rn_bf16(float x) {
    uint_t u = __float_as_uint(x);
    return (ushort_t)((u + 0x7FFFu + ((u >> 16) & 1u)) >> 16);
}

// ---------------- K1: qkv projection, sync-free 32x32 MFMA tiles, inline rstd ----------------
// grid 256 x 192 (3 waves; 1 block/CU). wave-tile id = bid*3 + w: ot = id>>7, pt = id&127.
__global__ __launch_bounds__(192)
void k_qkv(const float* __restrict__ x, const float* __restrict__ w_qkv,
           const float* __restrict__ ln_w, ushort_t* __restrict__ QH,
           ushort_t* __restrict__ QKB)
{
    const int tid = threadIdx.x;
    const int w = tid >> 6, l = tid & 63;
    const int col = l & 31, half = l >> 5;
    const int id = (int)blockIdx.x * 3 + w;   // 0..767
    const int ot = id >> 7;                    // 0..5
    const int pt = id & 127;                   // 0..127
    const int obase = ot * 32;
    const int gpx = pt * 32 + col;

    float s = 0.f, s2 = 0.f;
    #pragma unroll 16
    for (int c = 0; c < 64; ++c) {
        float v = x[c * PIX + gpx];
        s += v; s2 = fmaf(v, v, s2);
    }
    const float mean = s * 0.015625f;
    const float var  = fmaf(-mean, mean, s2 * 0.015625f);
    const float rs   = 1.0f / sqrtf(var + 1e-5f);

    f32x16 acc = {0,0,0,0,0,0,0,0,0,0,0,0,0,0,0,0};
    const float* wrow = w_qkv + (obase + col) * 64;
    #pragma unroll
    for (int s4 = 0; s4 < 4; ++s4) {
        const int kbase = s4 * 16 + half * 8;
        float t8[8];
        *(float4*)&t8[0] = *(const float4*)&wrow[kbase];
        *(float4*)&t8[4] = *(const float4*)&wrow[kbase + 4];
        union { uint_t u[4]; bf16x8 b; } wa;
        #pragma unroll
        for (int j = 0; j < 4; ++j)
            wa.u[j] = (uint_t)rn_bf16(t8[2 * j]) | ((uint_t)rn_bf16(t8[2 * j + 1]) << 16);
        const float4 lwa = *(const float4*)&ln_w[kbase];
        const float4 lwb = *(const float4*)&ln_w[kbase + 4];
        float b8[8];
        b8[0] = x[(kbase + 0) * PIX + gpx] * rs * lwa.x;
        b8[1] = x[(kbase + 1) * PIX + gpx] * rs * lwa.y;
        b8[2] = x[(kbase + 2) * PIX + gpx] * rs * lwa.z;
        b8[3] = x[(kbase + 3) * PIX + gpx] * rs * lwa.w;
        b8[4] = x[(kbase + 4) * PIX + gpx] * rs * lwb.x;
        b8[5] = x[(kbase + 5) * PIX + gpx] * rs * lwb.y;
        b8[6] = x[(kbase + 6) * PIX + gpx] * rs * lwb.z;
        b8[7] = x[(kbase + 7) * PIX + gpx] * rs * lwb.w;
        union { uint_t u[4]; bf16x8 b; } xb;
        #pragma unroll
        for (int j = 0; j < 4; ++j)
            xb.u[j] = (uint_t)rn_bf16(b8[2 * j]) | ((uint_t)rn_bf16(b8[2 * j + 1]) << 16);
        acc = __builtin_amdgcn_mfma_f32_32x32x16_bf16(wa.b, xb.b, acc, 0, 0, 0);
    }

    #pragma unroll
    for (int j = 0; j < 16; ++j) {
        const int o = obase + (j & 3) + 8 * (j >> 2) + 4 * half;
        if (o < 64) {
            QH[((o >> 4) * PIX + gpx) * 16 + (o & 15)] = rn_bf16(acc[j] * QSCALE);
        } else {
            QKB[(o - 64) * PIX + gpx] = rn_bf16(acc[j]);
        }
    }
}

// ---------------- K2: K + V unfold-gather from bf16, 8 elems/thread (unchanged) ----------------
__global__ __launch_bounds__(256)
void k_prep_kv(const ushort_t* __restrict__ QKB,
               ushort_t* __restrict__ KF, ushort_t* __restrict__ VF)
{
    const int bid = blockIdx.x;
    const int tid = threadIdx.x;
    if (bid < 288) {
        const int t = bid * 256 + tid;          // < 73728
        const int h = t / 18432; int r = t - h * 18432;
        const int i = r >> 6;   const int l = r & 63;
        const int col = l & 31, rl = l >> 5;
        const int m = i * 32 + col;
        const int cc = m / 576;  const int r3 = m - cc * 576;
        const int orr = r3 / 48; const int r4 = r3 - orr * 48;
        const int oc = r4 >> 2, wg = r4 & 3;
        const int row = wg * 16 + rl * 8 + orr - 2;
        const bool rowOk = (unsigned)row < 64u;
        const ushort_t* src = QKB + (h * 16 + cc) * PIX + row * 64 + (oc - 2);
        union { ushort_t us[8]; bf16x8 b; } o8;
        #pragma unroll
        for (int j = 0; j < 8; ++j) {
            const int colp = j * 8 + oc - 2;
            o8.us[j] = (rowOk && (unsigned)colp < 64u) ? src[j * 8] : (ushort_t)0;
        }
        *(bf16x8*)&KF[(h * 288 + i) * 512 + l * 8] = o8.b;
    } else {
        const int t = (bid - 288) * 256 + tid;  // < 73728
        const int h = t / 18432; int r = t - h * 18432;
        const int i = r >> 6;   const int r2 = r & 63;
        const int half = r2 >> 5; const int rl = (r2 >> 4) & 1; const int colD = r2 & 15;
        const int d = colD;
        const int vcolp = (d & 7) * 8 - 2;
        const int rbase = (d >> 3) * 8 - 2;
        const ushort_t* srcp = QKB + (64 + h * 16) * PIX;
        union { ushort_t us[8]; bf16x8 b; } o8;
        #pragma unroll
        for (int j2 = 0; j2 < 8; ++j2) {
            const int m = i * 32 + half * 16 + rl * 4 + (j2 & 3) + 8 * (j2 >> 2);
            const int cc = m / 576;  const int r3 = m - cc * 576;
            const int orr = r3 / 48; const int r4 = r3 - orr * 48;
            const int oc = r4 >> 2, wg = r4 & 3;
            const int row  = wg * 16 + rbase + orr;
            const int colp = vcolp + oc;
            const bool ok = ((unsigned)row < 64u) && ((unsigned)colp < 64u);
            o8.us[j2] = ok ? srcp[cc * PIX + row * 64 + colp] : (ushort_t)0;
        }
        *(bf16x8*)&VF[(h * 288 + i) * 512 + half * 256 + (rl * 16 + colD) * 8] = o8.b;
    }
}

// ---------------- K3: MFMA attention, 16 waves/block (ksplit=16 in-block), LDS combine ----------------
// grid 256 x 1024. bid: x=bid&7 -> h=x>>1, tileLSB=x&1; tile=((bid>>3)<<1)|(x&1) in 0..63.
// 16 waves/CU = 4 waves/SIMD; partials combined + den-divided in LDS; writes dense AO f32.
__global__ __launch_bounds__(1024, 4)
void k_attn(const ushort_t* __restrict__ QH,
            const ushort_t* __restrict__ KF, const ushort_t* __restrict__ VF,
            float* __restrict__ AO)
{
    __shared__ float racc[16][64][18];   // 72 KB

    const int tid = threadIdx.x;
    const int w   = tid >> 6;       // ks = w, 0..15
    const int l   = tid & 63;
    const int col = l & 31;
    const int rl  = l >> 5;

    const int bid  = blockIdx.x;
    const int x    = bid & 7;
    const int h    = x >> 1;
    const int tile = ((bid >> 3) << 1) | (x & 1);   // 0..63, 64 queries each
    const int qbase = tile * 64;

    const ushort_t* Qb = QH + ((h << 12) + qbase + col) * 16 + rl * 8;
    const bf16x8 qh0 = *(const bf16x8*)&Qb[0];
    const bf16x8 qh1 = *(const bf16x8*)&Qb[512];    // +32 pixels * 16

    f32x16 acc0 = {0,0,0,0,0,0,0,0,0,0,0,0,0,0,0,0};
    f32x16 acc1 = {0,0,0,0,0,0,0,0,0,0,0,0,0,0,0,0};
    const f32x16 zero = {0,0,0,0,0,0,0,0,0,0,0,0,0,0,0,0};

    union { uint_t u[4]; bf16x8 b; } vconst;
    const uint_t cfill = (col == 16) ? 0x3F803F80u : 0u;
    vconst.u[0] = cfill; vconst.u[1] = cfill; vconst.u[2] = cfill; vconst.u[3] = cfill;

    const ushort_t* kb = KF + (h * 288 + w * 18) * 512;
    const ushort_t* vb = VF + (h * 288 + w * 18) * 512;
    const int vl = (rl * 16 + (col & 15)) * 8;
    const bool vload = (col < 16);

    bf16x8 kh = *(const bf16x8*)&kb[l * 8];
    bf16x8 v0 = vconst.b, v1 = vconst.b;
    if (vload) {
        v0 = *(const bf16x8*)&vb[vl];
        v1 = *(const bf16x8*)&vb[256 + vl];
    }

    for (int i = 0; i < 18; ++i) {
        const bf16x8 ckh = kh, cv0 = v0, cv1 = v1;
        if (i < 17) {
            kb += 512; vb += 512;
            kh = *(const bf16x8*)&kb[l * 8];
            if (vload) {
                v0 = *(const bf16x8*)&vb[vl];
                v1 = *(const bf16x8*)&vb[256 + vl];
            }
        }

        f32x16 S0 = __builtin_amdgcn_mfma_f32_32x32x16_bf16(ckh, qh0, zero, 0, 0, 0);
        f32x16 S1 = __builtin_amdgcn_mfma_f32_32x32x16_bf16(ckh, qh1, zero, 0, 0, 0);

        {
            float p[16];
            #pragma unroll
            for (int r = 0; r < 16; ++r) p[r] = EXP2F(S0[r]);
            union { uint_t u[4]; bf16x8 b; } A0, A1;
            #pragma unroll
            for (int j = 0; j < 4; ++j) {
                A0.u[j] = PKHI16(__float_as_uint(p[2 * j + 1]), __float_as_uint(p[2 * j]));
                A1.u[j] = PKHI16(__float_as_uint(p[8 + 2 * j + 1]), __float_as_uint(p[8 + 2 * j]));
            }
            acc0 = __builtin_amdgcn_mfma_f32_32x32x16_bf16(A0.b, cv0, acc0, 0, 0, 0);
            acc0 = __builtin_amdgcn_mfma_f32_32x32x16_bf16(A1.b, cv1, acc0, 0, 0, 0);
        }
        {
            float p[16];
            #pragma unroll
            for (int r = 0; r < 16; ++r) p[r] = EXP2F(S1[r]);
            union { uint_t u[4]; bf16x8 b; } A0, A1;
            #pragma unroll
            for (int j = 0; j < 4; ++j) {
                A0.u[j] = PKHI16(__float_as_uint(p[2 * j + 1]), __float_as_uint(p[2 * j]));
                A1.u[j] = PKHI16(__float_as_uint(p[8 + 2 * j + 1]), __float_as_uint(p[8 + 2 * j]));
            }
            acc1 = __builtin_amdgcn_mfma_f32_32x32x16_bf16(A0.b, cv0, acc1, 0, 0, 0);
            acc1 = __builtin_amdgcn_mfma_f32_32x32x16_bf16(A1.b, cv1, acc1, 0, 0, 0);
        }
    }

    // in-block combine: store partials (cols 0-15 = PV, col 16 = den)
    if (col <= 16) {
        #pragma unroll
        for (int j = 0; j < 16; ++j) {
            const int q0 = (j & 3) + 8 * (j >> 2) + 4 * rl;   // 0..31
            racc[w][q0][col]      = acc0[j];
            racc[w][32 + q0][col] = acc1[j];
        }
    }
    __syncthreads();

    // 1024 threads -> (q 0..63, d 0..15): sum 16 partials, divide, store AO
    const int q = tid >> 4, d = tid & 15;
    float sum = 0.f, den = 0.f;
    #pragma unroll
    for (int ww = 0; ww < 16; ++ww) {
        sum += racc[ww][q][d];
        den += racc[ww][q][16];
    }
    AO[(qbase + q) * 64 + h * 16 + d] = sum / den;
}

// ---------------- K4: output projection (dense AO, no combine) ----------------
// grid 256 (16 px each), block 256
__global__ __launch_bounds__(256)
void k_proj(const float* __restrict__ AO, const float* __restrict__ w_out,
            float* __restrict__ out)
{
    __shared__ float as2[16 * 68];
    __shared__ float wo[64 * 68];
    const int tid = threadIdx.x;
    const int pbase = blockIdx.x * 16;

    for (int idx = tid; idx < 1024; idx += 256) {
        int pl = idx >> 6, i = idx & 63;
        as2[pl * 68 + i] = AO[(pbase + pl) * 64 + i];
    }
    for (int idx = tid; idx < 4096; idx += 256)
        wo[(idx >> 6) * 68 + (idx & 63)] = w_out[idx];
    __syncthreads();

    const int pl = tid & 15;
    const int og = tid >> 4;
    float a0 = 0.f, a1 = 0.f, a2 = 0.f, a3 = 0.f;
    for (int c = 0; c < 64; c += 4) {
        const float4 xv = *(const float4*)&as2[pl * 68 + c];
        const float4 w0 = *(const float4*)&wo[(og * 4 + 0) * 68 + c];
        const float4 w1 = *(const float4*)&wo[(og * 4 + 1) * 68 + c];
        const float4 w2 = *(const float4*)&wo[(og * 4 + 2) * 68 + c];
        const float4 w3 = *(const float4*)&wo[(og * 4 + 3) * 68 + c];
        a0 = fmaf(xv.x, w0.x, fmaf(xv.y, w0.y, fmaf(xv.z, w0.z, fmaf(xv.w, w0.w, a0))));
        a1 = fmaf(xv.x, w1.x, fmaf(xv.y, w1.y, fmaf(xv.z, w1.z, fmaf(xv.w, w1.w, a1))));
        a2 = fmaf(xv.x, w2.x, fmaf(xv.y, w2.y, fmaf(xv.z, w2.z, fmaf(xv.w, w2.w, a2))));
        a3 = fmaf(xv.x, w3.x, fmaf(xv.y, w3.y, fmaf(xv.z, w3.z, fmaf(xv.w, w3.w, a3))));
    }
    out[(og * 4 + 0) * PIX + pbase + pl] = a0;
    out[(og * 4 + 1) * PIX + pbase + pl] = a1;
    out[(og * 4 + 2) * PIX + pbase + pl] = a2;
    out[(og * 4 + 3) * PIX + pbase + pl] = a3;
}

extern "C" void kernel_launch(void* const* d_in, const int* in_sizes, int n_in,
                              void* d_out, int out_size, void* d_ws, size_t ws_size,
                              hipStream_t stream)
{
    const float* x     = (const float*)d_in[0];
    const float* w_qkv = (const float*)d_in[1];
    const float* w_out = (const float*)d_in[2];
    const float* ln_w  = (const float*)d_in[3];
    float* out = (float*)d_out;
    float* ws  = (float*)d_ws;

    float* AO = ws;
    ushort_t* U  = (ushort_t*)(ws + OFF_USHORT);
    ushort_t* QH  = U + U_QH;
    ushort_t* QKB = U + U_QKB;
    ushort_t* KF  = U + U_KF;
    ushort_t* VF  = U + U_VF;

    k_qkv     <<<dim3(256), dim3(192),  0, stream>>>(x, w_qkv, ln_w, QH, QKB);
    k_prep_kv <<<dim3(576), dim3(256),  0, stream>>>(QKB, KF, VF);
    k_attn    <<<dim3(256), dim3(1024), 0, stream>>>(QH, KF, VF, AO);
    k_proj    <<<dim3(256), dim3(256),  0, stream>>>(AO, w_out, out);
}